// Round 1
// baseline (1826.940 us; speedup 1.0000x reference)
//
#include <hip/hip_runtime.h>

#define TT 256
#define CONDL 192
#define PREDL 64
#define HH 256
#define BB 4096
#define BT 16            // batch tile per block
#define NTHR 512         // 8 waves, 2 per SIMD
#define HFR 4096         // shorts per h buffer: 8 kt * 64 lanes * 8

typedef short bf16x8 __attribute__((ext_vector_type(8)));
typedef float f32x4 __attribute__((ext_vector_type(4)));
typedef unsigned short u16x4 __attribute__((ext_vector_type(4)));

__device__ __forceinline__ short f2bf(float f) {
  unsigned u = __builtin_bit_cast(unsigned, f);
  unsigned r = (u + 0x7fffu + ((u >> 16) & 1u)) >> 16;
  return (short)r;
}
__device__ __forceinline__ float bf2f(short s) {
  unsigned u = ((unsigned)(unsigned short)s) << 16;
  return __builtin_bit_cast(float, u);
}
__device__ __forceinline__ float bflo(unsigned p) {
  return __builtin_bit_cast(float, p << 16);
}
__device__ __forceinline__ float bfhi(unsigned p) {
  return __builtin_bit_cast(float, p & 0xffff0000u);
}
__device__ __forceinline__ float sig_(float x) {
  return __builtin_amdgcn_rcpf(1.0f + __builtin_amdgcn_exp2f(-1.44269504f * x));
}
__device__ __forceinline__ float tanh_(float x) {
  float e = __builtin_amdgcn_exp2f(2.88539008f * x);  // exp(2x)
  return 1.0f - 2.0f * __builtin_amdgcn_rcpf(e + 1.0f);
}

// Pack w_hh [1024][256] fp32 -> bf16 B-fragments in exact MFMA operand order:
// frag (jt,kt): lane holds W[n = jt*16 + (lane&15)][k = kt*32 + (lane>>4)*8 + 0..7]
__global__ void pack_w(const float* __restrict__ w_hh, short* __restrict__ wp) {
  int idx = blockIdx.x * 256 + threadIdx.x;   // 64 jt * 8 kt * 64 lanes
  int lane = idx & 63;
  int kt = (idx >> 6) & 7;
  int jt = idx >> 9;
  int n = jt * 16 + (lane & 15);
  int k0 = kt * 32 + (lane >> 4) * 8;
  bf16x8 v;
#pragma unroll
  for (int j = 0; j < 8; ++j) v[j] = f2bf(w_hh[n * 256 + k0 + j]);
  *(bf16x8*)(wp + (long)idx * 8) = v;
}

__global__ __launch_bounds__(NTHR, 2)
void lstm_main(const float* __restrict__ cd, const float* __restrict__ pred,
               const float* __restrict__ w_ih, const float* __restrict__ b_ih,
               const float* __restrict__ b_hh, const float* __restrict__ w_out,
               const float* __restrict__ b_out, const short* __restrict__ wp,
               float* __restrict__ out) {
  // LDS: h dbuf 16 KB (MFMA-frag order) + x 8 KB = 24 KB
  __shared__ __align__(16) short h_s[2 * HFR];
  __shared__ __align__(16) short x_s[TT * BT];

  const int tid = threadIdx.x;
  const int lane = tid & 63;
  const int wv = tid >> 6;        // wave 0..7
  const int r0 = blockIdx.x * BT;
  const int lm = lane & 15;
  const int lq = lane >> 4;
  const int m0 = lq * 4;

  const bf16x8* wpf = (const bf16x8*)wp;

  // ---- one-time staging ----
  for (int i = tid; i < BT * CONDL; i += NTHR) {
    int r = i / CONDL, t = i % CONDL;
    x_s[t * BT + r] = f2bf(cd[(r0 + r) * CONDL + t]);
  }
  for (int i = tid; i < BT * PREDL; i += NTHR) {
    int r = i / PREDL, t = i % PREDL;
    x_s[(CONDL + t) * BT + r] = f2bf(pred[(r0 + r) * PREDL + t]);
  }
  for (int i = tid; i < HFR; i += NTHR) h_s[i] = 0;  // h_0 = 0, buffer 0

  // All 4 gates' weight fragments in registers: a = g*2 + i, g in 0..3,
  // i = subtile (wave owns subtiles wv*2 + {0,1}). 64 frags = 256 regs.
  bf16x8 wreg[64];
#pragma unroll
  for (int a = 0; a < 8; ++a) {
    int jt = (a >> 1) * 16 + wv * 2 + (a & 1);
#pragma unroll
    for (int kt = 0; kt < 8; ++kt)
      wreg[a * 8 + kt] = wpf[(jt * 8 + kt) * 64 + lane];
  }
#pragma unroll
  for (int i = 0; i < 64; ++i) asm volatile("" : "+v"(wreg[i]));

  // packed (w_ih, b_ih+b_hh) bf16 pairs; index a = g*2+i, g in 0..3
  unsigned wbs[8];
#pragma unroll
  for (int a = 0; a < 8; ++a) {
    int j = (a >> 1) * 256 + (wv * 2 + (a & 1)) * 16 + lm;
    unsigned lo = (unsigned short)f2bf(w_ih[j]);
    unsigned hi = (unsigned short)f2bf(b_ih[j] + b_hh[j]);
    wbs[a] = lo | (hi << 16);
  }

  // h write offsets (short index into frag-ordered buffer).
  // Value h[r][u]: kt = u>>5 (= wv for our units), lane l = (r&15)|(((u>>3)&3)<<4),
  // elem j = u&7 -> idx = kt*512 + l*8 + j.
  int wo[8];
#pragma unroll
  for (int i = 0; i < 2; ++i)
#pragma unroll
    for (int v = 0; v < 4; ++v)
      wo[i * 4 + v] =
          wv * 512 + ((lq * 4 + v) | ((2 * i + (lm >> 3)) << 4)) * 8 + (lm & 7);

  float cst[8];   // cell state: subtile i (2) x batch row v (4)
#pragma unroll
  for (int i = 0; i < 8; ++i) cst[i] = 0.f;

  f32x4 zero4;
  zero4[0] = 0.f; zero4[1] = 0.f; zero4[2] = 0.f; zero4[3] = 0.f;

  __syncthreads();

  // ---- recurrence ----
  for (int t = 0; t < TT; ++t) {
    const short* hr = h_s + (t & 1) * HFR;
    short* hw = h_s + ((t + 1) & 1) * HFR;

    // A-fragments: lane-linear, conflict-free ds_read_b128
    bf16x8 af[8];
#pragma unroll
    for (int kt = 0; kt < 8; ++kt)
      af[kt] = *(const bf16x8*)(hr + kt * 512 + lane * 8);

    f32x4 acc[8];
    // subtile-0 chains (a even) first ...
#pragma unroll
    for (int kt = 0; kt < 8; ++kt) {
#pragma unroll
      for (int g = 0; g < 4; ++g)
        acc[g * 2] = __builtin_amdgcn_mfma_f32_16x16x32_bf16(
            af[kt], wreg[(g * 2) * 8 + kt], (kt == 0) ? zero4 : acc[g * 2],
            0, 0, 0);
    }

    u16x4 xq = *(const u16x4*)(x_s + t * BT + m0);

    // ... then subtile-1 chains; ELEM(subtile 0) below overlaps their drain
#pragma unroll
    for (int kt = 0; kt < 8; ++kt) {
#pragma unroll
      for (int g = 0; g < 4; ++g)
        acc[g * 2 + 1] = __builtin_amdgcn_mfma_f32_16x16x32_bf16(
            af[kt], wreg[(g * 2 + 1) * 8 + kt],
            (kt == 0) ? zero4 : acc[g * 2 + 1], 0, 0, 0);
    }

    float xr[4];
#pragma unroll
    for (int v = 0; v < 4; ++v) xr[v] = bf2f((short)xq[v]);

    // LSTM elementwise; i=0 emitted first -> overlaps subtile-1 MFMA drain
#pragma unroll
    for (int i = 0; i < 2; ++i) {
      float wI = bflo(wbs[i]),     bI = bfhi(wbs[i]);
      float wF = bflo(wbs[2 + i]), bF = bfhi(wbs[2 + i]);
      float wG = bflo(wbs[4 + i]), bG = bfhi(wbs[4 + i]);
      float wO = bflo(wbs[6 + i]), bO = bfhi(wbs[6 + i]);
#pragma unroll
      for (int v = 0; v < 4; ++v) {
        float ig = sig_(acc[i][v]     + xr[v] * wI + bI);
        float fg = sig_(acc[2 + i][v] + xr[v] * wF + bF);
        float gg = tanh_(acc[4 + i][v] + xr[v] * wG + bG);
        float og = sig_(acc[6 + i][v] + xr[v] * wO + bO);
        float cn = fg * cst[i * 4 + v] + ig * gg;
        cst[i * 4 + v] = cn;
        hw[wo[i * 4 + v]] = f2bf(og * tanh_(cn));
      }
    }
    __syncthreads();
  }

  // ---- readout: out[r] = sigmoid(h_last . w_out + b_out); buffer 0 (T even) ----
  const short* hf = h_s;
  float bo = b_out[0];
#pragma unroll
  for (int rr = 0; rr < 2; ++rr) {
    int row = wv * 2 + rr;
    float p = 0.f;
#pragma unroll
    for (int c = 0; c < 4; ++c) {
      int k = lane + c * 64;
      int idx = (k >> 5) * 512 + (row | (((k >> 3) & 3) << 4)) * 8 + (k & 7);
      p += bf2f(hf[idx]) * w_out[k];
    }
#pragma unroll
    for (int off = 32; off > 0; off >>= 1) p += __shfl_down(p, off);
    if (lane == 0) out[r0 + row] = sig_(p + bo);
  }
}

extern "C" void kernel_launch(void* const* d_in, const int* in_sizes, int n_in,
                              void* d_out, int out_size, void* d_ws, size_t ws_size,
                              hipStream_t stream) {
  const float* cd    = (const float*)d_in[0];
  const float* pr    = (const float*)d_in[1];
  const float* w_ih  = (const float*)d_in[2];
  const float* w_hh  = (const float*)d_in[3];
  const float* b_ih  = (const float*)d_in[4];
  const float* b_hh  = (const float*)d_in[5];
  const float* w_out = (const float*)d_in[6];
  const float* b_out = (const float*)d_in[7];
  float* out = (float*)d_out;
  short* wp = (short*)d_ws;   // 512 KB packed bf16 weights

  pack_w<<<128, 256, 0, stream>>>(w_hh, wp);
  lstm_main<<<256, NTHR, 0, stream>>>(cd, pr, w_ih, b_ih, b_hh, w_out, b_out, wp, out);
}

// Round 2
// 763.585 us; speedup vs baseline: 2.3926x; 2.3926x over previous
//
#include <hip/hip_runtime.h>

#define TT 256
#define CONDL 192
#define PREDL 64
#define HH 256
#define BB 4096
#define BT 16            // batch tile per block
#define NTHR 512         // 8 waves, 2 per SIMD
#define HFR 4096         // shorts per h buffer: 8 kt * 64 lanes * 8

typedef short bf16x8 __attribute__((ext_vector_type(8)));
typedef float f32x4 __attribute__((ext_vector_type(4)));
typedef unsigned short u16x4 __attribute__((ext_vector_type(4)));

__device__ __forceinline__ short f2bf(float f) {
  unsigned u = __builtin_bit_cast(unsigned, f);
  unsigned r = (u + 0x7fffu + ((u >> 16) & 1u)) >> 16;
  return (short)r;
}
__device__ __forceinline__ float bf2f(short s) {
  unsigned u = ((unsigned)(unsigned short)s) << 16;
  return __builtin_bit_cast(float, u);
}
__device__ __forceinline__ float bflo(unsigned p) {
  return __builtin_bit_cast(float, p << 16);
}
__device__ __forceinline__ float bfhi(unsigned p) {
  return __builtin_bit_cast(float, p & 0xffff0000u);
}
__device__ __forceinline__ float sig_(float x) {
  return __builtin_amdgcn_rcpf(1.0f + __builtin_amdgcn_exp2f(-1.44269504f * x));
}
__device__ __forceinline__ float tanh_(float x) {
  float e = __builtin_amdgcn_exp2f(2.88539008f * x);  // exp(2x)
  return 1.0f - 2.0f * __builtin_amdgcn_rcpf(e + 1.0f);
}

// Pack w_hh [1024][256] fp32 -> bf16 B-fragments in exact MFMA operand order:
// frag (jt,kt): lane holds W[n = jt*16 + (lane&15)][k = kt*32 + (lane>>4)*8 + 0..7]
__global__ void pack_w(const float* __restrict__ w_hh, short* __restrict__ wp) {
  int idx = blockIdx.x * 256 + threadIdx.x;   // 64 jt * 8 kt * 64 lanes
  int lane = idx & 63;
  int kt = (idx >> 6) & 7;
  int jt = idx >> 9;
  int n = jt * 16 + (lane & 15);
  int k0 = kt * 32 + (lane >> 4) * 8;
  bf16x8 v;
#pragma unroll
  for (int j = 0; j < 8; ++j) v[j] = f2bf(w_hh[n * 256 + k0 + j]);
  *(bf16x8*)(wp + (long)idx * 8) = v;
}

__global__ __launch_bounds__(NTHR, 2)
void lstm_main(const float* __restrict__ cd, const float* __restrict__ pred,
               const float* __restrict__ w_ih, const float* __restrict__ b_ih,
               const float* __restrict__ b_hh, const float* __restrict__ w_out,
               const float* __restrict__ b_out, const short* __restrict__ wp,
               float* __restrict__ out) {
  // LDS: o-gate weights 128 KB + h dbuf 16 KB (frag order) + x 8 KB = 152 KB
  __shared__ __align__(16) short lds_w[16 * 8 * 64 * 8];
  __shared__ __align__(16) short h_s[2 * HFR];
  __shared__ __align__(16) short x_s[TT * BT];

  const int tid = threadIdx.x;
  const int lane = tid & 63;
  const int wv = tid >> 6;        // wave 0..7
  const int r0 = blockIdx.x * BT;
  const int lm = lane & 15;
  const int lq = lane >> 4;
  const int m0 = lq * 4;

  const bf16x8* wpf = (const bf16x8*)wp;
  bf16x8* ldsw = (bf16x8*)lds_w;

  // ---- one-time staging ----
  for (int i = tid; i < BT * CONDL; i += NTHR) {
    int r = i / CONDL, t = i % CONDL;
    x_s[t * BT + r] = f2bf(cd[(r0 + r) * CONDL + t]);
  }
  for (int i = tid; i < BT * PREDL; i += NTHR) {
    int r = i / PREDL, t = i % PREDL;
    x_s[(CONDL + t) * BT + r] = f2bf(pred[(r0 + r) * PREDL + t]);
  }
  for (int i = tid; i < HFR; i += NTHR) h_s[i] = 0;  // h_0 = 0, buffer 0

  // o-gate (g==3) weight frags -> LDS, frag order, lane-linear (conflict-free)
#pragma unroll
  for (int i = 0; i < 2; ++i) {
    int st = wv * 2 + i;
#pragma unroll
    for (int kt = 0; kt < 8; ++kt)
      ldsw[(st * 8 + kt) * 64 + lane] = wpf[((48 + st) * 8 + kt) * 64 + lane];
  }

  // VGPR-resident tiles: gates i,f,g (a = g*2+i, g<3) = 48 frags = 192 regs
  bf16x8 wreg[48];
#pragma unroll
  for (int a = 0; a < 6; ++a) {
    int jt = (a >> 1) * 16 + wv * 2 + (a & 1);
#pragma unroll
    for (int kt = 0; kt < 8; ++kt)
      wreg[a * 8 + kt] = wpf[(jt * 8 + kt) * 64 + lane];
  }
#pragma unroll
  for (int i = 0; i < 48; ++i) asm volatile("" : "+v"(wreg[i]));

  // packed (w_ih, b_ih+b_hh) bf16 pairs; index a = g*2+i, g in 0..3
  unsigned wbs[8];
#pragma unroll
  for (int a = 0; a < 8; ++a) {
    int j = (a >> 1) * 256 + (wv * 2 + (a & 1)) * 16 + lm;
    unsigned lo = (unsigned short)f2bf(w_ih[j]);
    unsigned hi = (unsigned short)f2bf(b_ih[j] + b_hh[j]);
    wbs[a] = lo | (hi << 16);
  }

  // h write offsets (short index into frag-ordered buffer).
  // Value h[r][u]: kt = u>>5 (= wv for our units), lane l = (r&15)|(((u>>3)&3)<<4),
  // elem j = u&7 -> idx = kt*512 + l*8 + j.   (verified in Round 1)
  int wo[8];
#pragma unroll
  for (int i = 0; i < 2; ++i)
#pragma unroll
    for (int v = 0; v < 4; ++v)
      wo[i * 4 + v] =
          wv * 512 + ((lq * 4 + v) | ((2 * i + (lm >> 3)) << 4)) * 8 + (lm & 7);

  float cst[8];   // cell state: subtile i (2) x batch row v (4)
#pragma unroll
  for (int i = 0; i < 8; ++i) cst[i] = 0.f;

  f32x4 zero4;
  zero4[0] = 0.f; zero4[1] = 0.f; zero4[2] = 0.f; zero4[3] = 0.f;

  __syncthreads();

  // ---- recurrence ----
  for (int t = 0; t < TT; ++t) {
    const short* hr = h_s + (t & 1) * HFR;
    short* hw = h_s + ((t + 1) & 1) * HFR;

    f32x4 acc[8];   // chains: a = g*2+i, g=0..3

    // pass 1: subtile 0 chains (a even); af loaded per-kt (keeps pressure low)
#pragma unroll
    for (int kt = 0; kt < 8; ++kt) {
      bf16x8 af = *(const bf16x8*)(hr + kt * 512 + lane * 8);
      bf16x8 wo0 = ldsw[((wv * 2) * 8 + kt) * 64 + lane];
      acc[0] = __builtin_amdgcn_mfma_f32_16x16x32_bf16(
          af, wreg[0 * 8 + kt], (kt == 0) ? zero4 : acc[0], 0, 0, 0);
      acc[2] = __builtin_amdgcn_mfma_f32_16x16x32_bf16(
          af, wreg[2 * 8 + kt], (kt == 0) ? zero4 : acc[2], 0, 0, 0);
      acc[4] = __builtin_amdgcn_mfma_f32_16x16x32_bf16(
          af, wreg[4 * 8 + kt], (kt == 0) ? zero4 : acc[4], 0, 0, 0);
      acc[6] = __builtin_amdgcn_mfma_f32_16x16x32_bf16(
          af, wo0, (kt == 0) ? zero4 : acc[6], 0, 0, 0);
    }

    // x_t for this lane's 4 batch rows (issue early, consumed in ELEM)
    u16x4 xq = *(const u16x4*)(x_s + t * BT + m0);

    // pass 2: subtile 1 chains (a odd); ELEM(0) below overlaps their drain
#pragma unroll
    for (int kt = 0; kt < 8; ++kt) {
      bf16x8 af = *(const bf16x8*)(hr + kt * 512 + lane * 8);
      bf16x8 wo1 = ldsw[((wv * 2 + 1) * 8 + kt) * 64 + lane];
      acc[1] = __builtin_amdgcn_mfma_f32_16x16x32_bf16(
          af, wreg[1 * 8 + kt], (kt == 0) ? zero4 : acc[1], 0, 0, 0);
      acc[3] = __builtin_amdgcn_mfma_f32_16x16x32_bf16(
          af, wreg[3 * 8 + kt], (kt == 0) ? zero4 : acc[3], 0, 0, 0);
      acc[5] = __builtin_amdgcn_mfma_f32_16x16x32_bf16(
          af, wreg[5 * 8 + kt], (kt == 0) ? zero4 : acc[5], 0, 0, 0);
      acc[7] = __builtin_amdgcn_mfma_f32_16x16x32_bf16(
          af, wo1, (kt == 0) ? zero4 : acc[7], 0, 0, 0);
    }

    float xr[4];
#pragma unroll
    for (int v = 0; v < 4; ++v) xr[v] = bf2f((short)xq[v]);

    // LSTM elementwise; i=0 consumes pass-1 accs -> overlaps pass-2 MFMA drain
#pragma unroll
    for (int i = 0; i < 2; ++i) {
      float wI = bflo(wbs[i]),     bI = bfhi(wbs[i]);
      float wF = bflo(wbs[2 + i]), bF = bfhi(wbs[2 + i]);
      float wG = bflo(wbs[4 + i]), bG = bfhi(wbs[4 + i]);
      float wO = bflo(wbs[6 + i]), bO = bfhi(wbs[6 + i]);
#pragma unroll
      for (int v = 0; v < 4; ++v) {
        float ig = sig_(acc[i][v]     + xr[v] * wI + bI);
        float fg = sig_(acc[2 + i][v] + xr[v] * wF + bF);
        float gg = tanh_(acc[4 + i][v] + xr[v] * wG + bG);
        float og = sig_(acc[6 + i][v] + xr[v] * wO + bO);
        float cn = fg * cst[i * 4 + v] + ig * gg;
        cst[i * 4 + v] = cn;
        hw[wo[i * 4 + v]] = f2bf(og * tanh_(cn));
      }
    }
    __syncthreads();
  }

  // ---- readout: out[r] = sigmoid(h_last . w_out + b_out); buffer 0 (T even) ----
  const short* hf = h_s;
  float bo = b_out[0];
#pragma unroll
  for (int rr = 0; rr < 2; ++rr) {
    int row = wv * 2 + rr;
    float p = 0.f;
#pragma unroll
    for (int c = 0; c < 4; ++c) {
      int k = lane + c * 64;
      int idx = (k >> 5) * 512 + (row | (((k >> 3) & 3) << 4)) * 8 + (k & 7);
      p += bf2f(hf[idx]) * w_out[k];
    }
#pragma unroll
    for (int off = 32; off > 0; off >>= 1) p += __shfl_down(p, off);
    if (lane == 0) out[r0 + row] = sig_(p + bo);
  }
}

extern "C" void kernel_launch(void* const* d_in, const int* in_sizes, int n_in,
                              void* d_out, int out_size, void* d_ws, size_t ws_size,
                              hipStream_t stream) {
  const float* cd    = (const float*)d_in[0];
  const float* pr    = (const float*)d_in[1];
  const float* w_ih  = (const float*)d_in[2];
  const float* w_hh  = (const float*)d_in[3];
  const float* b_ih  = (const float*)d_in[4];
  const float* b_hh  = (const float*)d_in[5];
  const float* w_out = (const float*)d_in[6];
  const float* b_out = (const float*)d_in[7];
  float* out = (float*)d_out;
  short* wp = (short*)d_ws;   // 512 KB packed bf16 weights

  pack_w<<<128, 256, 0, stream>>>(w_hh, wp);
  lstm_main<<<256, NTHR, 0, stream>>>(cd, pr, w_ih, b_ih, b_hh, w_out, b_out, wp, out);
}